// Round 1
// baseline (88.073 us; speedup 1.0000x reference)
//
#include <hip/hip_runtime.h>

typedef __attribute__((ext_vector_type(8))) short short8;
typedef __attribute__((ext_vector_type(4))) float f32x4;
typedef __attribute__((ext_vector_type(4))) int i32x4;
typedef __attribute__((ext_vector_type(4))) unsigned u32x4;

// fp32 -> bf16 round-to-nearest-even
__device__ __forceinline__ unsigned short f2bf(float f) {
  unsigned u = __builtin_bit_cast(unsigned, f);
  u += 0x7fffu + ((u >> 16) & 1u);
  return (unsigned short)(u >> 16);
}

// ---------------------------------------------------------------------------
// prep_stats: per (b,i): mean over K, max1/max2/argmax over K (exact LOO max),
// and copy the fp32 user part into out0 (cols 0..127 of each row).
// ---------------------------------------------------------------------------
__global__ void prep_stats(const float* __restrict__ user,
                           float* __restrict__ out0,
                           float* __restrict__ mean,
                           float* __restrict__ max1,
                           float* __restrict__ max2,
                           int* __restrict__ argm) {
  int idx = blockIdx.x * 256 + threadIdx.x;  // 0..131071  (B*IN)
  int b = idx >> 7, i = idx & 127;
  const float* up = user + (size_t)(b * 64) * 128 + i;
  float* op = out0 + (size_t)(b * 64) * 384 + i;
  float s = 0.f, m1 = -3.402823466e38f, m2 = -3.402823466e38f;
  int am = 0;
  #pragma unroll 8
  for (int k = 0; k < 64; ++k) {
    float u = up[(size_t)k * 128];
    op[(size_t)k * 384] = u;
    s += u;
    if (u > m1) { m2 = m1; m1 = u; am = k; }
    else if (u > m2) { m2 = u; }
  }
  mean[idx] = s * (1.f / 64.f);
  max1[idx] = m1;
  max2[idx] = m2;
  argm[idx] = am;
}

// ---------------------------------------------------------------------------
// prep_w: convert W1..W4 (fp32 row-major [K][N]) into bf16, pre-swizzled into
// MFMA-16x16x32 B-fragment order: elem (kk,n) -> block(nb=n/16, kb=kk/32),
// lane = (n&15) | (((kk>>3)&3)<<4), j = kk&7.
// ---------------------------------------------------------------------------
__global__ void prep_w(const float* __restrict__ W1, const float* __restrict__ W2,
                       const float* __restrict__ W3, const float* __restrict__ W4,
                       unsigned short* __restrict__ W1f, unsigned short* __restrict__ W2f,
                       unsigned short* __restrict__ W3f, unsigned short* __restrict__ W4f) {
  int idx = blockIdx.x * 256 + threadIdx.x;  // 0..294911
  const float* src; unsigned short* dst; int kb; int rel;
  if (idx < 98304)        { src = W1; dst = W1f; kb = 12; rel = idx; }
  else if (idx < 163840)  { src = W2; dst = W2f; kb = 8;  rel = idx - 98304; }
  else if (idx < 229376)  { src = W3; dst = W3f; kb = 8;  rel = idx - 163840; }
  else                    { src = W4; dst = W4f; kb = 8;  rel = idx - 229376; }
  int kk = rel >> 8, n = rel & 255;
  int lane = (n & 15) | (((kk >> 3) & 3) << 4);
  int di = (((n >> 4) * kb + (kk >> 5)) * 64 + lane) * 8 + (kk & 7);
  dst[di] = f2bf(src[rel]);
}

// ---------------------------------------------------------------------------
// fused 2-layer MLP, 128-row x 256-col tile, 8 waves (2Mx4N), bf16 MFMA.
// MODE 0: user path. A = [user | loo | ris_bcast], K1=384. out = out0 h-part.
// MODE 1: RIS path.  A = [ris  | mean],            K1=256. out = out1 (also
//                    copies fp32 ris into out1 cols 0..127).
// ---------------------------------------------------------------------------
template<int MODE>
__global__ __launch_bounds__(512, 1)
void fused_mlp(const float* __restrict__ srcA,
               const float* __restrict__ max1, const float* __restrict__ max2,
               const int* __restrict__ argm, const float* __restrict__ aux,
               const unsigned short* __restrict__ Wa,
               const unsigned short* __restrict__ Wb,
               const float* __restrict__ ba, const float* __restrict__ bb,
               float* __restrict__ out) {
  constexpr int NSTEP = (MODE == 0) ? 6 : 4;   // K1/64
  constexpr int KB1 = NSTEP * 2;               // K1/32
  __shared__ unsigned short A[128][72];        // 64-wide K chunk, pad->72 (16B rows, 2-way banks)
  __shared__ unsigned short H[128][264];       // h1 tile, pad->264 (16B rows, 2-way banks)

  const int tid = threadIdx.x;
  const int lane = tid & 63, wid = tid >> 6;
  const int wm = wid >> 2, wn = wid & 3;       // wave tile: 64 rows x 64 cols
  const int row0 = blockIdx.x * 128;
  const int sr = tid >> 2;                     // staging: row 0..127
  const int sc = (tid & 3) << 4;               // staging: col base (16 elems)

  f32x4 acc[4][4];
  #pragma unroll
  for (int a = 0; a < 4; ++a)
    #pragma unroll
    for (int q = 0; q < 4; ++q) acc[a][q] = (f32x4)0.f;

  #pragma unroll
  for (int s = 0; s < NSTEP; ++s) {
    float v[16];
    if constexpr (MODE == 0) {
      if (s < 2) {
        const float* p = &srcA[(size_t)(row0 + sr) * 128 + s * 64 + sc];
        #pragma unroll
        for (int q = 0; q < 4; ++q) {
          f32x4 t = *(const f32x4*)(p + q * 4);
          #pragma unroll
          for (int jj = 0; jj < 4; ++jj) v[q * 4 + jj] = t[jj];
        }
      } else if (s < 4) {
        int R = row0 + sr; int bi = R >> 6, kk = R & 63;
        int ib = bi * 128 + (s - 2) * 64 + sc;
        #pragma unroll
        for (int q = 0; q < 4; ++q) {
          i32x4 aq = *(const i32x4*)(argm + ib + q * 4);
          f32x4 m1q = *(const f32x4*)(max1 + ib + q * 4);
          f32x4 m2q = *(const f32x4*)(max2 + ib + q * 4);
          #pragma unroll
          for (int jj = 0; jj < 4; ++jj)
            v[q * 4 + jj] = (aq[jj] == kk) ? m2q[jj] : m1q[jj];
        }
      } else {
        int bi = (row0 + sr) >> 6;
        const float* p = &aux[bi * 128 + (s - 4) * 64 + sc];
        #pragma unroll
        for (int q = 0; q < 4; ++q) {
          f32x4 t = *(const f32x4*)(p + q * 4);
          #pragma unroll
          for (int jj = 0; jj < 4; ++jj) v[q * 4 + jj] = t[jj];
        }
      }
    } else {
      const float* p = (s < 2) ? &srcA[(size_t)(row0 + sr) * 128 + s * 64 + sc]
                               : &aux[(size_t)(row0 + sr) * 128 + (s - 2) * 64 + sc];
      #pragma unroll
      for (int q = 0; q < 4; ++q) {
        f32x4 t = *(const f32x4*)(p + q * 4);
        #pragma unroll
        for (int jj = 0; jj < 4; ++jj) v[q * 4 + jj] = t[jj];
      }
      if (s < 2) {  // exact fp32 copy of RIS into out1 cols 0..127
        float* o = &out[(size_t)(row0 + sr) * 384 + s * 64 + sc];
        #pragma unroll
        for (int q = 0; q < 4; ++q) {
          f32x4 t = *(const f32x4*)(&v[q * 4]);
          *(f32x4*)(o + q * 4) = t;
        }
      }
    }
    __syncthreads();  // previous chunk's MFMA reads of A done
    unsigned pk[8];
    #pragma unroll
    for (int j = 0; j < 8; ++j)
      pk[j] = (unsigned)f2bf(v[2 * j]) | ((unsigned)f2bf(v[2 * j + 1]) << 16);
    u32x4 w0 = {pk[0], pk[1], pk[2], pk[3]};
    u32x4 w1 = {pk[4], pk[5], pk[6], pk[7]};
    *(u32x4*)&A[sr][sc] = w0;
    *(u32x4*)&A[sr][sc + 8] = w1;
    __syncthreads();
    #pragma unroll
    for (int ks = 0; ks < 2; ++ks) {
      short8 af[4], bfr[4];
      #pragma unroll
      for (int mf = 0; mf < 4; ++mf)
        af[mf] = *(const short8*)&A[wm * 64 + mf * 16 + (lane & 15)][ks * 32 + (lane >> 4) * 8];
      #pragma unroll
      for (int nf = 0; nf < 4; ++nf)
        bfr[nf] = *(const short8*)&Wa[(size_t)(((wn * 4 + nf) * KB1 + (s * 2 + ks)) * 64 + lane) * 8];
      #pragma unroll
      for (int mf = 0; mf < 4; ++mf)
        #pragma unroll
        for (int nf = 0; nf < 4; ++nf)
          acc[mf][nf] = __builtin_amdgcn_mfma_f32_16x16x32_bf16(af[mf], bfr[nf], acc[mf][nf], 0, 0, 0);
    }
  }

  // ---- layer-1 epilogue: bias + relu -> H (bf16) ----
  float bav[4];
  #pragma unroll
  for (int nf = 0; nf < 4; ++nf) bav[nf] = ba[wn * 64 + nf * 16 + (lane & 15)];
  #pragma unroll
  for (int mf = 0; mf < 4; ++mf)
    #pragma unroll
    for (int nf = 0; nf < 4; ++nf)
      #pragma unroll
      for (int j = 0; j < 4; ++j) {
        int row = wm * 64 + mf * 16 + ((lane >> 4) * 4) + j;
        int col = wn * 64 + nf * 16 + (lane & 15);
        float hv = acc[mf][nf][j] + bav[nf];
        H[row][col] = f2bf(fmaxf(hv, 0.f));
      }
  __syncthreads();

  // ---- layer 2: H(128x256) @ Wb(256x256) ----
  #pragma unroll
  for (int a = 0; a < 4; ++a)
    #pragma unroll
    for (int q = 0; q < 4; ++q) acc[a][q] = (f32x4)0.f;
  #pragma unroll
  for (int kc = 0; kc < 8; ++kc) {
    short8 af[4], bfr[4];
    #pragma unroll
    for (int mf = 0; mf < 4; ++mf)
      af[mf] = *(const short8*)&H[wm * 64 + mf * 16 + (lane & 15)][kc * 32 + (lane >> 4) * 8];
    #pragma unroll
    for (int nf = 0; nf < 4; ++nf)
      bfr[nf] = *(const short8*)&Wb[(size_t)(((wn * 4 + nf) * 8 + kc) * 64 + lane) * 8];
    #pragma unroll
    for (int mf = 0; mf < 4; ++mf)
      #pragma unroll
      for (int nf = 0; nf < 4; ++nf)
        acc[mf][nf] = __builtin_amdgcn_mfma_f32_16x16x32_bf16(af[mf], bfr[nf], acc[mf][nf], 0, 0, 0);
  }

  // ---- layer-2 epilogue: bias, fp32 store to out cols 128..383 ----
  float bbv[4];
  #pragma unroll
  for (int nf = 0; nf < 4; ++nf) bbv[nf] = bb[wn * 64 + nf * 16 + (lane & 15)];
  #pragma unroll
  for (int mf = 0; mf < 4; ++mf)
    #pragma unroll
    for (int nf = 0; nf < 4; ++nf)
      #pragma unroll
      for (int j = 0; j < 4; ++j) {
        int row = wm * 64 + mf * 16 + ((lane >> 4) * 4) + j;
        int col = wn * 64 + nf * 16 + (lane & 15);
        out[(size_t)(row0 + row) * 384 + 128 + col] = acc[mf][nf][j] + bbv[nf];
      }
}

// ---------------------------------------------------------------------------
extern "C" void kernel_launch(void* const* d_in, const int* in_sizes, int n_in,
                              void* d_out, int out_size, void* d_ws, size_t ws_size,
                              hipStream_t stream) {
  const float* user = (const float*)d_in[0];
  const float* ris  = (const float*)d_in[1];
  // d_in[2] cas_channel, d_in[3] d_link: unused by reference
  const float* W1 = (const float*)d_in[4];
  const float* b1 = (const float*)d_in[5];
  const float* W2 = (const float*)d_in[6];
  const float* b2 = (const float*)d_in[7];
  const float* W3 = (const float*)d_in[8];
  const float* b3 = (const float*)d_in[9];
  const float* W4 = (const float*)d_in[10];
  const float* b4 = (const float*)d_in[11];

  float* out0 = (float*)d_out;                         // (65536, 384)
  float* out1 = out0 + (size_t)65536 * 384;            // (1024, 384)

  char* ws = (char*)d_ws;
  float* mean = (float*)(ws);                          // 131072 f32
  float* max1 = (float*)(ws + 524288);
  float* max2 = (float*)(ws + 1048576);
  int*   argm = (int*)(ws + 1572864);
  unsigned short* W1f = (unsigned short*)(ws + 2097152);  // 98304 bf16
  unsigned short* W2f = (unsigned short*)(ws + 2293760);  // 65536 bf16
  unsigned short* W3f = (unsigned short*)(ws + 2424832);  // 65536 bf16
  unsigned short* W4f = (unsigned short*)(ws + 2555904);  // 65536 bf16

  hipLaunchKernelGGL(prep_stats, dim3(512), dim3(256), 0, stream,
                     user, out0, mean, max1, max2, argm);
  hipLaunchKernelGGL(prep_w, dim3(1152), dim3(256), 0, stream,
                     W1, W2, W3, W4, W1f, W2f, W3f, W4f);
  hipLaunchKernelGGL((fused_mlp<0>), dim3(512), dim3(512), 0, stream,
                     user, max1, max2, argm, ris, W1f, W2f, b1, b2, out0);
  hipLaunchKernelGGL((fused_mlp<1>), dim3(8), dim3(512), 0, stream,
                     ris, nullptr, nullptr, nullptr, mean, W3f, W4f, b3, b4, out1);
}

// Round 2
// 71.903 us; speedup vs baseline: 1.2249x; 1.2249x over previous
//
#include <hip/hip_runtime.h>

typedef __attribute__((ext_vector_type(8))) short short8;
typedef __attribute__((ext_vector_type(4))) float f32x4;
typedef __attribute__((ext_vector_type(4))) int i32x4;
typedef __attribute__((ext_vector_type(4))) unsigned u32x4;

// fp32 -> bf16 round-to-nearest-even
__device__ __forceinline__ unsigned short f2bf(float f) {
  unsigned u = __builtin_bit_cast(unsigned, f);
  u += 0x7fffu + ((u >> 16) & 1u);
  return (unsigned short)(u >> 16);
}

// ---------------------------------------------------------------------------
// prep: blocks [0,512): per-(b,i) stats (mean, max1, max2, argmax).
//       blocks [512,1664): W1..W4 fp32 -> bf16 MFMA B-fragment swizzle.
// ---------------------------------------------------------------------------
__global__ __launch_bounds__(256) void prep(
    const float* __restrict__ user,
    const float* __restrict__ W1, const float* __restrict__ W2,
    const float* __restrict__ W3, const float* __restrict__ W4,
    float* __restrict__ mean, float* __restrict__ max1,
    float* __restrict__ max2, int* __restrict__ argm,
    unsigned short* __restrict__ W1f, unsigned short* __restrict__ W2f,
    unsigned short* __restrict__ W3f, unsigned short* __restrict__ W4f) {
  if (blockIdx.x < 512) {
    int idx = blockIdx.x * 256 + threadIdx.x;  // 0..131071 (B*IN)
    int b = idx >> 7, i = idx & 127;
    const float* up = user + (size_t)(b * 64) * 128 + i;
    float s = 0.f, m1 = -3.402823466e38f, m2 = -3.402823466e38f;
    int am = 0;
    #pragma unroll 8
    for (int k = 0; k < 64; ++k) {
      float u = up[(size_t)k * 128];
      s += u;
      if (u > m1) { m2 = m1; m1 = u; am = k; }
      else if (u > m2) { m2 = u; }
    }
    mean[idx] = s * (1.f / 64.f);
    max1[idx] = m1;
    max2[idx] = m2;
    argm[idx] = am;
  } else {
    int idx = (blockIdx.x - 512) * 256 + threadIdx.x;  // 0..294911
    const float* src; unsigned short* dst; int kb; int rel;
    if (idx < 98304)        { src = W1; dst = W1f; kb = 12; rel = idx; }
    else if (idx < 163840)  { src = W2; dst = W2f; kb = 8;  rel = idx - 98304; }
    else if (idx < 229376)  { src = W3; dst = W3f; kb = 8;  rel = idx - 163840; }
    else                    { src = W4; dst = W4f; kb = 8;  rel = idx - 229376; }
    int kk = rel >> 8, n = rel & 255;
    int lane = (n & 15) | (((kk >> 3) & 3) << 4);
    int di = (((n >> 4) * kb + (kk >> 5)) * 64 + lane) * 8 + (kk & 7);
    dst[di] = f2bf(src[rel]);
  }
}

// ---------------------------------------------------------------------------
// fused 2-layer MLP, 64-row x 256-col tile, 4 waves (1M x 4N), bf16 MFMA.
// A double-buffered + XOR-swizzled LDS; H XOR-swizzled LDS.
// MODE 0: user path, K1=384 (user|loo|ris_bcast); block = one batch b.
// MODE 1: RIS path,  K1=256 (ris|mean).
// Both modes also write the exact fp32 copy part (cols 0..127) of out.
// ---------------------------------------------------------------------------
template<int MODE>
__device__ __forceinline__ void mlp_body(
    int bx, unsigned short* __restrict__ Abuf, unsigned short* __restrict__ Hb,
    const float* __restrict__ srcA,
    const float* __restrict__ max1, const float* __restrict__ max2,
    const int* __restrict__ argm, const float* __restrict__ aux,
    const unsigned short* __restrict__ Wa, const unsigned short* __restrict__ Wb,
    const float* __restrict__ ba, const float* __restrict__ bb,
    float* __restrict__ out) {
  constexpr int NSTEP = (MODE == 0) ? 6 : 4;   // K1/64
  constexpr int KB1 = NSTEP * 2;               // K1/32

  const int tid = threadIdx.x;
  const int lane = tid & 63, wn = tid >> 6;    // 4 waves, N-split
  const int row0 = bx * 64;
  const int sr = tid >> 2;                     // staging row 0..63
  const int sc = (tid & 3) << 4;               // staging col base (shorts)
  const int bidx = row0 >> 6;                  // batch index (MODE 0)

  // ---- staging load: 16 fp32 per thread for K-chunk s ----
  auto load_step = [&](int s, float* v) {
    if constexpr (MODE == 0) {
      if (s < 2) {
        const float* p = &srcA[(size_t)(row0 + sr) * 128 + s * 64 + sc];
        #pragma unroll
        for (int q = 0; q < 4; ++q) {
          f32x4 t = *(const f32x4*)(p + q * 4);
          #pragma unroll
          for (int jj = 0; jj < 4; ++jj) v[q * 4 + jj] = t[jj];
        }
      } else if (s < 4) {
        int ib = bidx * 128 + (s - 2) * 64 + sc;
        #pragma unroll
        for (int q = 0; q < 4; ++q) {
          i32x4 aq = *(const i32x4*)(argm + ib + q * 4);
          f32x4 m1q = *(const f32x4*)(max1 + ib + q * 4);
          f32x4 m2q = *(const f32x4*)(max2 + ib + q * 4);
          #pragma unroll
          for (int jj = 0; jj < 4; ++jj)
            v[q * 4 + jj] = (aq[jj] == sr) ? m2q[jj] : m1q[jj];
        }
      } else {
        const float* p = &aux[bidx * 128 + (s - 4) * 64 + sc];
        #pragma unroll
        for (int q = 0; q < 4; ++q) {
          f32x4 t = *(const f32x4*)(p + q * 4);
          #pragma unroll
          for (int jj = 0; jj < 4; ++jj) v[q * 4 + jj] = t[jj];
        }
      }
    } else {
      const float* p = (s < 2) ? &srcA[(size_t)(row0 + sr) * 128 + s * 64 + sc]
                               : &aux[(size_t)(row0 + sr) * 128 + (s - 2) * 64 + sc];
      #pragma unroll
      for (int q = 0; q < 4; ++q) {
        f32x4 t = *(const f32x4*)(p + q * 4);
        #pragma unroll
        for (int jj = 0; jj < 4; ++jj) v[q * 4 + jj] = t[jj];
      }
    }
  };

  // ---- convert + swizzled LDS write (+ fp32 copy part of out for s<2) ----
  auto stage_write = [&](int buf, int s, const float* v) {
    if (s < 2) {  // exact fp32 copy into out cols 0..127
      float* o = &out[(size_t)(row0 + sr) * 384 + s * 64 + sc];
      #pragma unroll
      for (int q = 0; q < 4; ++q) {
        f32x4 t = {v[q * 4 + 0], v[q * 4 + 1], v[q * 4 + 2], v[q * 4 + 3]};
        *(f32x4*)(o + q * 4) = t;
      }
    }
    unsigned pk[8];
    #pragma unroll
    for (int j = 0; j < 8; ++j)
      pk[j] = (unsigned)f2bf(v[2 * j]) | ((unsigned)f2bf(v[2 * j + 1]) << 16);
    unsigned short* base = Abuf + buf * (64 * 64) + sr * 64;
    int c0 = (tid & 3) * 2, k = sr & 7;
    u32x4 w0 = {pk[0], pk[1], pk[2], pk[3]};
    u32x4 w1 = {pk[4], pk[5], pk[6], pk[7]};
    *(u32x4*)(base + ((c0 ^ k) << 3)) = w0;
    *(u32x4*)(base + (((c0 + 1) ^ k) << 3)) = w1;
  };

  f32x4 acc[4][4];
  #pragma unroll
  for (int a = 0; a < 4; ++a)
    #pragma unroll
    for (int q = 0; q < 4; ++q) acc[a][q] = (f32x4)0.f;

  // ---- layer 1: A(64xK1) @ Wa(K1x256), double-buffered staging ----
  {
    float v0[16];
    load_step(0, v0);
    stage_write(0, 0, v0);
  }
  __syncthreads();
  #pragma unroll
  for (int s = 0; s < NSTEP; ++s) {
    float nv[16];
    if (s + 1 < NSTEP) load_step(s + 1, nv);   // loads in flight during MFMAs
    const unsigned short* Ab = Abuf + (s & 1) * (64 * 64);
    #pragma unroll
    for (int ks = 0; ks < 2; ++ks) {
      short8 af[4], bfr[4];
      #pragma unroll
      for (int mf = 0; mf < 4; ++mf) {
        int r = mf * 16 + (lane & 15);
        int c = ks * 4 + (lane >> 4);
        af[mf] = *(const short8*)(Ab + r * 64 + ((c ^ (r & 7)) << 3));
      }
      #pragma unroll
      for (int nf = 0; nf < 4; ++nf)
        bfr[nf] = *(const short8*)&Wa[(size_t)(((wn * 4 + nf) * KB1 + (s * 2 + ks)) * 64 + lane) * 8];
      #pragma unroll
      for (int mf = 0; mf < 4; ++mf)
        #pragma unroll
        for (int nf = 0; nf < 4; ++nf)
          acc[mf][nf] = __builtin_amdgcn_mfma_f32_16x16x32_bf16(af[mf], bfr[nf], acc[mf][nf], 0, 0, 0);
    }
    if (s + 1 < NSTEP) stage_write((s + 1) & 1, s + 1, nv);
    __syncthreads();
  }

  // ---- layer-1 epilogue: bias + relu -> H (bf16, swizzled) ----
  float bav[4];
  #pragma unroll
  for (int nf = 0; nf < 4; ++nf) bav[nf] = ba[wn * 64 + nf * 16 + (lane & 15)];
  #pragma unroll
  for (int mf = 0; mf < 4; ++mf)
    #pragma unroll
    for (int nf = 0; nf < 4; ++nf)
      #pragma unroll
      for (int j = 0; j < 4; ++j) {
        int r = mf * 16 + ((lane >> 4) * 4) + j;
        int col = wn * 64 + nf * 16 + (lane & 15);
        int c = col >> 3;
        Hb[r * 256 + ((c ^ (r & 7)) << 3) + (col & 7)] =
            f2bf(fmaxf(acc[mf][nf][j] + bav[nf], 0.f));
      }
  __syncthreads();

  // ---- layer 2: H(64x256) @ Wb(256x256) ----
  #pragma unroll
  for (int a = 0; a < 4; ++a)
    #pragma unroll
    for (int q = 0; q < 4; ++q) acc[a][q] = (f32x4)0.f;
  #pragma unroll
  for (int kc = 0; kc < 8; ++kc) {
    short8 af[4], bfr[4];
    #pragma unroll
    for (int mf = 0; mf < 4; ++mf) {
      int r = mf * 16 + (lane & 15);
      int c = kc * 4 + (lane >> 4);
      af[mf] = *(const short8*)(Hb + r * 256 + ((c ^ (r & 7)) << 3));
    }
    #pragma unroll
    for (int nf = 0; nf < 4; ++nf)
      bfr[nf] = *(const short8*)&Wb[(size_t)(((wn * 4 + nf) * 8 + kc) * 64 + lane) * 8];
    #pragma unroll
    for (int mf = 0; mf < 4; ++mf)
      #pragma unroll
      for (int nf = 0; nf < 4; ++nf)
        acc[mf][nf] = __builtin_amdgcn_mfma_f32_16x16x32_bf16(af[mf], bfr[nf], acc[mf][nf], 0, 0, 0);
  }

  // ---- layer-2 epilogue: bias, fp32 store to out cols 128..383 ----
  float bbv[4];
  #pragma unroll
  for (int nf = 0; nf < 4; ++nf) bbv[nf] = bb[wn * 64 + nf * 16 + (lane & 15)];
  #pragma unroll
  for (int mf = 0; mf < 4; ++mf)
    #pragma unroll
    for (int nf = 0; nf < 4; ++nf)
      #pragma unroll
      for (int j = 0; j < 4; ++j) {
        int r = mf * 16 + ((lane >> 4) * 4) + j;
        int col = wn * 64 + nf * 16 + (lane & 15);
        out[(size_t)(row0 + r) * 384 + 128 + col] = acc[mf][nf][j] + bbv[nf];
      }
}

__global__ __launch_bounds__(256, 3) void fused(
    const float* __restrict__ user, const float* __restrict__ ris,
    const float* __restrict__ max1, const float* __restrict__ max2,
    const int* __restrict__ argm, const float* __restrict__ mean,
    const unsigned short* __restrict__ W1f, const unsigned short* __restrict__ W2f,
    const unsigned short* __restrict__ W3f, const unsigned short* __restrict__ W4f,
    const float* __restrict__ b1, const float* __restrict__ b2,
    const float* __restrict__ b3, const float* __restrict__ b4,
    float* __restrict__ out0, float* __restrict__ out1) {
  __shared__ unsigned short Abuf[2 * 64 * 64];   // 16 KiB, XOR-swizzled
  __shared__ unsigned short Hb[64 * 256];        // 32 KiB, XOR-swizzled
  if (blockIdx.x < 1024)
    mlp_body<0>(blockIdx.x, Abuf, Hb, user, max1, max2, argm, ris,
                W1f, W2f, b1, b2, out0);
  else
    mlp_body<1>(blockIdx.x - 1024, Abuf, Hb, ris, nullptr, nullptr, nullptr,
                mean, W3f, W4f, b3, b4, out1);
}

// ---------------------------------------------------------------------------
extern "C" void kernel_launch(void* const* d_in, const int* in_sizes, int n_in,
                              void* d_out, int out_size, void* d_ws, size_t ws_size,
                              hipStream_t stream) {
  const float* user = (const float*)d_in[0];
  const float* ris  = (const float*)d_in[1];
  const float* W1 = (const float*)d_in[4];
  const float* b1 = (const float*)d_in[5];
  const float* W2 = (const float*)d_in[6];
  const float* b2 = (const float*)d_in[7];
  const float* W3 = (const float*)d_in[8];
  const float* b3 = (const float*)d_in[9];
  const float* W4 = (const float*)d_in[10];
  const float* b4 = (const float*)d_in[11];

  float* out0 = (float*)d_out;                         // (65536, 384)
  float* out1 = out0 + (size_t)65536 * 384;            // (1024, 384)

  char* ws = (char*)d_ws;
  float* mean = (float*)(ws);                          // 131072 f32 each
  float* max1 = (float*)(ws + 524288);
  float* max2 = (float*)(ws + 1048576);
  int*   argm = (int*)(ws + 1572864);
  unsigned short* W1f = (unsigned short*)(ws + 2097152);  // 98304 bf16
  unsigned short* W2f = (unsigned short*)(ws + 2293760);  // 65536 bf16
  unsigned short* W3f = (unsigned short*)(ws + 2424832);  // 65536 bf16
  unsigned short* W4f = (unsigned short*)(ws + 2555904);  // 65536 bf16

  hipLaunchKernelGGL(prep, dim3(1664), dim3(256), 0, stream,
                     user, W1, W2, W3, W4, mean, max1, max2, argm,
                     W1f, W2f, W3f, W4f);
  hipLaunchKernelGGL(fused, dim3(1040), dim3(256), 0, stream,
                     user, ris, max1, max2, argm, mean,
                     W1f, W2f, W3f, W4f, b1, b2, b3, b4, out0, out1);
}